// Round 9
// baseline (121.315 us; speedup 1.0000x reference)
//
#include <hip/hip_runtime.h>

typedef float f32x4 __attribute__((ext_vector_type(4)));

// Geometry: L = 16384 tokens, Lc = 8192 chunks, H = 4096 hidden
// EMA recurrence y_i = A_i*y_{i-1} + Pc_i*concept_i  (A_i scalar, shared over H)
//
// Pipeline (2 kernels):
//   setup: decode mask -> start[], A[], Pc[]  (1 block)
//   scan_fused (grid 2048): per (segment=16 chunks, 1024-channel group) block:
//     - batch-load own 16 concept rows to regs
//     - carry = sum_{j<i0} (prod A in gap) * Pc[j] * concept[j], computed via
//       64-chunk windows: wave0 does a shfl product-scan of A to get per-chunk
//       coefs (LDS), ballot-truncated at 1e-12 (A[0]=0 guarantees termination);
//       channel lanes accumulate the ~30 surviving L3-hot rows.
//     - rescan segment from carry, NT-write token rows.

#define SEG 16
#define TPB 256
#define SETUP_T 1024
#define TOL 1e-12f

// ---------------- setup ----------------
__global__ void __launch_bounds__(SETUP_T)
setup_kernel(const unsigned char* __restrict__ mask,
             const float* __restrict__ probs,
             float* __restrict__ A, float* __restrict__ Pc,
             int* __restrict__ start, int L, int Lc) {
    __shared__ int flag;
    __shared__ int wsum[SETUP_T / 64];
    const int t = threadIdx.x;
    const int lane = t & 63, wv = t >> 6;
    if (t == 0) flag = 0;
    __syncthreads();

    // 16 tokens per thread (L == 16384)
    int4 v8 = ((const int4*)mask)[t];   // 16 bytes, u8 view
    // encoding detect: int32 0/1 data has all bytes at pos%4!=0 zero
    int f = (v8.x & (int)0xFFFFFF00) | (v8.y & (int)0xFFFFFF00) |
            (v8.z & (int)0xFFFFFF00) | (v8.w & (int)0xFFFFFF00);
    if (f) atomicOr(&flag, 1);
    __syncthreads();
    const bool isU8 = (flag != 0);

    unsigned mbits = 0;
    if (isU8) {
        unsigned dw[4] = {(unsigned)v8.x, (unsigned)v8.y, (unsigned)v8.z, (unsigned)v8.w};
#pragma unroll
        for (int q = 0; q < 4; ++q)
#pragma unroll
            for (int b = 0; b < 4; ++b)
                if ((dw[q] >> (8 * b)) & 0xFFu) mbits |= 1u << (q * 4 + b);
    } else {
        const int4* m4 = (const int4*)mask;   // i32 view
#pragma unroll
        for (int q = 0; q < 4; ++q) {
            int4 w = m4[t * 4 + q];
            if (w.x) mbits |= 1u << (q * 4 + 0);
            if (w.y) mbits |= 1u << (q * 4 + 1);
            if (w.z) mbits |= 1u << (q * 4 + 2);
            if (w.w) mbits |= 1u << (q * 4 + 3);
        }
    }
    int c = __popc(mbits);

    int s = c;
#pragma unroll
    for (int off = 1; off < 64; off <<= 1) {
        int v = __shfl_up(s, off, 64);
        if (lane >= off) s += v;
    }
    if (lane == 63) wsum[wv] = s;
    __syncthreads();
    if (t == 0) {
        int acc = 0;
        for (int w = 0; w < SETUP_T / 64; ++w) { int x = wsum[w]; wsum[w] = acc; acc += x; }
    }
    __syncthreads();

    int rank = wsum[wv] + (s - c);          // exclusive prefix
    const int t0 = t * 16;
#pragma unroll
    for (int k = 0; k < 16; ++k) {
        if ((mbits >> k) & 1u) {
            if (rank < Lc) {
                int tok = t0 + k;
                start[rank] = tok;
                float p = probs[tok];
                A[rank]  = (rank == 0) ? 0.0f : (1.0f - p);
                Pc[rank] = (rank == 0) ? 1.0f : p;
            }
            rank++;
        }
    }
    if (t == 0) start[Lc] = L;
}

// ---------------- fused: direct truncated carry + rescan + NT writes ----------------
__global__ void __launch_bounds__(TPB)
scan_fused_kernel(const float* __restrict__ cpt,
                  const float* __restrict__ A, const float* __restrict__ Pc,
                  const int* __restrict__ start,
                  float* __restrict__ out, int H, int CG) {
    const int g  = blockIdx.x / CG;
    const int cg = blockIdx.x % CG;
    const int ch = cg * (TPB * 4) + threadIdx.x * 4;
    const int i0 = g * SEG;

    __shared__ float sA[SEG], sP[SEG];
    __shared__ int   sS[SEG + 1];
    __shared__ float tcoef[64];
    __shared__ float sh_wnext;
    __shared__ int   sh_nt;
    if (threadIdx.x < SEG)     { sA[threadIdx.x] = A[i0 + threadIdx.x]; sP[threadIdx.x] = Pc[i0 + threadIdx.x]; }
    if (threadIdx.x < SEG + 1) { sS[threadIdx.x] = start[i0 + threadIdx.x]; }

    // batch own-segment concept rows (HBM; issue before carry phase)
    const int strideF4 = H / 4;
    const f32x4* cp = (const f32x4*)(cpt + (size_t)i0 * H + ch);
    f32x4 c[SEG];
#pragma unroll
    for (int k = 0; k < SEG; ++k) c[k] = cp[(size_t)k * strideF4];

    // ---- carry: windowed backward walk over raw concept rows ----
    f32x4 y = {0.f, 0.f, 0.f, 0.f};
    int jw = i0 - 1;             // highest chunk idx in current window
    float wbase = 1.0f;
    while (jw >= 0) {
        if (threadIdx.x < 64) {
            const int lane = threadIdx.x;
            const int j = jw - lane;
            const float a = (j >= 0) ? A[j]  : 0.0f;
            const float p = (j >= 0) ? Pc[j] : 0.0f;
            float s = a;                         // inclusive product scan
#pragma unroll
            for (int off = 1; off < 64; off <<= 1) {
                float v = __shfl_up(s, off, 64);
                if (lane >= off) s *= v;
            }
            float E = __shfl_up(s, 1, 64);       // exclusive
            if (lane == 0) E = 1.0f;
            E *= wbase;
            tcoef[lane] = E * p;
            if (lane == 63) sh_wnext = E * a;
            unsigned long long bal = __ballot(E < TOL);
            if (lane == 0) sh_nt = bal ? (__ffsll((long long)bal) - 1) : 64;
        }
        __syncthreads();
        const int nt = min(min(64, jw + 1), sh_nt);
        const f32x4* bp = (const f32x4*)(cpt + (size_t)jw * H + ch);
        for (int t = 0; t < nt; ++t) {
            y += tcoef[t] * bp[-(size_t)t * strideF4];
        }
        if (sh_nt < 64 || jw < 64) break;
        wbase = sh_wnext;
        jw -= 64;
        __syncthreads();
    }
    __syncthreads();   // sS/sA/sP staged above; ensure visible (also closes window loop)

    // ---- rescan from carry + NT token writes ----
#pragma unroll
    for (int k = 0; k < SEG; ++k) {
        y = sA[k] * y + sP[k] * c[k];
        const int ts = sS[k], te = sS[k + 1];
        for (int t = ts; t < te; ++t) {
            __builtin_nontemporal_store(y, (f32x4*)(out + (size_t)t * H + ch));
        }
    }
}

extern "C" void kernel_launch(void* const* d_in, const int* in_sizes, int n_in,
                              void* d_out, int out_size, void* d_ws, size_t ws_size,
                              hipStream_t stream) {
    const float* cpt   = (const float*)d_in[0];                 // [1, Lc, H] f32
    const float* probs = (const float*)d_in[1];                 // [1, L, 1] f32
    const unsigned char* mask = (const unsigned char*)d_in[2];  // [1, L] bool/int

    const int L  = in_sizes[1];           // 16384
    const int H  = out_size / L;          // 4096
    const int Lc = in_sizes[0] / H;       // 8192
    const int G  = Lc / SEG;              // 512
    const int CG = H / (TPB * 4);         // 4

    char* ws = (char*)d_ws;
    size_t off = 0;
    auto alloc = [&](size_t bytes) {
        size_t o = off;
        off += (bytes + 255) & ~(size_t)255;
        return (void*)(ws + o);
    };
    float* A     = (float*)alloc((size_t)Lc * 4);
    float* Pc    = (float*)alloc((size_t)Lc * 4);
    int*   start = (int*)  alloc((size_t)(Lc + 1) * 4);
    (void)ws_size;

    hipLaunchKernelGGL(setup_kernel, dim3(1), dim3(SETUP_T), 0, stream,
                       mask, probs, A, Pc, start, L, Lc);
    hipLaunchKernelGGL(scan_fused_kernel, dim3(G * CG), dim3(TPB), 0, stream,
                       cpt, A, Pc, start, (float*)d_out, H, CG);
}